// Round 1
// baseline (218.308 us; speedup 1.0000x reference)
//
#include <hip/hip_runtime.h>
#include <math.h>

#define EPS 1e-7f
#define FN_PENALTY 10.0f
#define BLOCK 256

typedef float  vf4 __attribute__((ext_vector_type(4)));

// Non-temporal 16-B load: global_load_dwordx4 with nt — bypasses L1 allocation.
__device__ __forceinline__ float4 ntload4f(const float4* p) {
    vf4 v = __builtin_nontemporal_load((const vf4*)p);
    float4 r; r.x = v.x; r.y = v.y; r.z = v.z; r.w = v.w;
    return r;
}
__device__ __forceinline__ int ntloadi(const int* p) {
    return __builtin_nontemporal_load(p);
}
__device__ __forceinline__ float ntloadf(const float* p) {
    return __builtin_nontemporal_load(p);
}

__device__ __forceinline__ float waveReduceSum(float v) {
    #pragma unroll
    for (int off = 32; off > 0; off >>= 1)
        v += __shfl_down(v, off, 64);
    return v;
}

__device__ __forceinline__ float4 validate_fix(float4 b) {
    bool invalid = (b.x > b.z) || (b.y > b.w);
    if (invalid) {
        b.x = fmaxf(b.x, 0.0f);
        b.y = fmaxf(b.y, 0.0f);
        b.z = fmaxf(b.z, 0.0f);
        b.w = fmaxf(b.w, 0.0f);
    }
    b.z = fmaxf(b.z, b.x + 1e-6f);
    b.w = fmaxf(b.w, b.y + 1e-6f);
    return b;
}

__device__ __forceinline__ void accum_row(
    float4 lg, int lbl, float4 pb, float4 tb, float cl, float ct,
    float& s_class, float& s_bbox, float& s_giou, float& s_cut)
{
    // ---- focal class loss ----
    float l0 = lg.x, l1 = lg.y, l2 = lg.z, l3 = lg.w;
    float m = fmaxf(fmaxf(l0, l1), fmaxf(l2, l3));
    float e0 = __expf(l0 - m), e1 = __expf(l1 - m),
          e2 = __expf(l2 - m), e3 = __expf(l3 - m);
    float se = e0 + e1 + e2 + e3;
    lbl &= 3;
    float lsel = (lbl == 0) ? l0 : (lbl == 1) ? l1 : (lbl == 2) ? l2 : l3;
    float esel = (lbl == 0) ? e0 : (lbl == 1) ? e1 : (lbl == 2) ? e2 : e3;
    float ce = __logf(se) + m - lsel;            // lse - lsel
    float pt = esel * __builtin_amdgcn_rcpf(se); // exp(-ce) == e_sel/se, rcp ∥ log
    float om = 1.0f - pt;
    s_class += om * om * ce;                     // ALPHA=1, GAMMA=2

    // ---- bbox L1 ----
    s_bbox += fabsf(pb.x - tb.x) + fabsf(pb.y - tb.y)
            + fabsf(pb.z - tb.z) + fabsf(pb.w - tb.w);

    // ---- GIoU ----
    float4 b1 = validate_fix(pb);
    float4 b2 = validate_fix(tb);
    float area1 = (b1.z - b1.x) * (b1.w - b1.y);
    float area2 = (b2.z - b2.x) * (b2.w - b2.y);
    float ltx = fmaxf(b1.x, b2.x), lty = fmaxf(b1.y, b2.y);
    float rbx = fminf(b1.z, b2.z), rby = fminf(b1.w, b2.w);
    float iw = fmaxf(rbx - ltx, 0.0f), ih = fmaxf(rby - lty, 0.0f);
    float inter = iw * ih;
    float uni = area1 + area2 - inter;
    float iou = __fdividef(inter, uni + EPS);
    float ex1 = fminf(b1.x, b2.x), ey1 = fminf(b1.y, b2.y);
    float ex2 = fmaxf(b1.z, b2.z), ey2 = fmaxf(b1.w, b2.w);
    float ew = fmaxf(ex2 - ex1, 0.0f), eh = fmaxf(ey2 - ey1, 0.0f);
    float enc = ew * eh;
    float giou = iou - __fdividef(enc - uni, enc + EPS);
    s_giou += fmaxf(1.0f - giou, 0.0f);

    // ---- weighted BCE ----
    float bce = fmaxf(cl, 0.0f) - cl * ct + __logf(1.0f + __expf(-fabsf(cl)));
    float w = ((ct == 1.0f) && (cl < 0.0f)) ? FN_PENALTY : 1.0f;  // sigmoid<0.5 <=> logit<0
    s_cut += bce * w;
}

__device__ __forceinline__ void block_reduce_store(
    float s_class, float s_bbox, float s_giou, float s_cut,
    float4* __restrict__ out_slot)
{
    s_class = waveReduceSum(s_class);
    s_bbox  = waveReduceSum(s_bbox);
    s_giou  = waveReduceSum(s_giou);
    s_cut   = waveReduceSum(s_cut);

    __shared__ float red[4][4];
    const int lane = threadIdx.x & 63;
    const int wave = threadIdx.x >> 6;
    if (lane == 0) {
        red[wave][0] = s_class;
        red[wave][1] = s_bbox;
        red[wave][2] = s_giou;
        red[wave][3] = s_cut;
    }
    __syncthreads();
    if (threadIdx.x == 0) {
        float4 r;
        r.x = red[0][0] + red[1][0] + red[2][0] + red[3][0];
        r.y = red[0][1] + red[1][1] + red[2][1] + red[3][1];
        r.z = red[0][2] + red[1][2] + red[2][2] + red[3][2];
        r.w = red[0][3] + red[1][3] + red[2][3] + red[3][3];
        *out_slot = r;
    }
}

// Stage 1: grid-stride, 4 rows per iteration, ALL loads non-temporal.
// 24 nt loads issued before the dependent compute of any row — the point is
// to force the register allocator to keep ~24 loads in flight per wave
// (previous build landed at VGPR=32, i.e. ~5-6 outstanding; MLP-starved).
__global__ __launch_bounds__(BLOCK) void loss_reduce(
    const float4* __restrict__ pred_logits,
    const int*    __restrict__ labels,
    const float4* __restrict__ pred_boxes,
    const float4* __restrict__ target_boxes,
    const float*  __restrict__ cut_logits,
    const float*  __restrict__ cut_targets,
    float4* __restrict__ block_out, int n)
{
    float s_class = 0.0f, s_bbox = 0.0f, s_giou = 0.0f, s_cut = 0.0f;
    const int T = gridDim.x * BLOCK;
    int i = blockIdx.x * BLOCK + threadIdx.x;

    for (; i + 3 * T < n; i += 4 * T) {
        const int i1 = i + T, i2 = i + 2 * T, i3 = i + 3 * T;
        // issue all 24 loads (nt) before any dependent use
        float4 lg0 = ntload4f(&pred_logits[i ]);
        float4 lg1 = ntload4f(&pred_logits[i1]);
        float4 lg2 = ntload4f(&pred_logits[i2]);
        float4 lg3 = ntload4f(&pred_logits[i3]);
        float4 pb0 = ntload4f(&pred_boxes[i ]);
        float4 pb1 = ntload4f(&pred_boxes[i1]);
        float4 pb2 = ntload4f(&pred_boxes[i2]);
        float4 pb3 = ntload4f(&pred_boxes[i3]);
        float4 tb0 = ntload4f(&target_boxes[i ]);
        float4 tb1 = ntload4f(&target_boxes[i1]);
        float4 tb2 = ntload4f(&target_boxes[i2]);
        float4 tb3 = ntload4f(&target_boxes[i3]);
        int    lb0 = ntloadi(&labels[i ]);
        int    lb1 = ntloadi(&labels[i1]);
        int    lb2 = ntloadi(&labels[i2]);
        int    lb3 = ntloadi(&labels[i3]);
        float  cl0 = ntloadf(&cut_logits[i ]);
        float  cl1 = ntloadf(&cut_logits[i1]);
        float  cl2 = ntloadf(&cut_logits[i2]);
        float  cl3 = ntloadf(&cut_logits[i3]);
        float  ct0 = ntloadf(&cut_targets[i ]);
        float  ct1 = ntloadf(&cut_targets[i1]);
        float  ct2 = ntloadf(&cut_targets[i2]);
        float  ct3 = ntloadf(&cut_targets[i3]);

        accum_row(lg0, lb0, pb0, tb0, cl0, ct0, s_class, s_bbox, s_giou, s_cut);
        accum_row(lg1, lb1, pb1, tb1, cl1, ct1, s_class, s_bbox, s_giou, s_cut);
        accum_row(lg2, lb2, pb2, tb2, cl2, ct2, s_class, s_bbox, s_giou, s_cut);
        accum_row(lg3, lb3, pb3, tb3, cl3, ct3, s_class, s_bbox, s_giou, s_cut);
    }
    for (; i < n; i += T) {
        accum_row(ntload4f(&pred_logits[i]), ntloadi(&labels[i]),
                  ntload4f(&pred_boxes[i]), ntload4f(&target_boxes[i]),
                  ntloadf(&cut_logits[i]), ntloadf(&cut_targets[i]),
                  s_class, s_bbox, s_giou, s_cut);
    }

    block_reduce_store(s_class, s_bbox, s_giou, s_cut, &block_out[blockIdx.x]);
}

// Stage 2 (merged 2+3): single block reduces all stage-1 partials and writes
// the 5 outputs. 2048 float4 = 32 KB read — ~2 µs; saves one launch gap.
__global__ __launch_bounds__(BLOCK) void finalize_all(
    const float4* __restrict__ in, int n,
    float* __restrict__ out, float inv_n)
{
    float c = 0.0f, b = 0.0f, g = 0.0f, u = 0.0f;
    for (int i = threadIdx.x; i < n; i += BLOCK) {
        float4 r = in[i];
        c += r.x; b += r.y; g += r.z; u += r.w;
    }
    c = waveReduceSum(c);
    b = waveReduceSum(b);
    g = waveReduceSum(g);
    u = waveReduceSum(u);

    __shared__ float red[4][4];
    const int lane = threadIdx.x & 63;
    const int wave = threadIdx.x >> 6;
    if (lane == 0) {
        red[wave][0] = c;
        red[wave][1] = b;
        red[wave][2] = g;
        red[wave][3] = u;
    }
    __syncthreads();
    if (threadIdx.x == 0) {
        float tc = red[0][0] + red[1][0] + red[2][0] + red[3][0];
        float tb = red[0][1] + red[1][1] + red[2][1] + red[3][1];
        float tg = red[0][2] + red[1][2] + red[2][2] + red[3][2];
        float tu = red[0][3] + red[1][3] + red[2][3] + red[3][3];
        float lc   = fmaxf(tc * inv_n, 0.0f);
        float lb   = fmaxf(tb * inv_n * 0.25f, 0.0f);  // mean over 4N elems
        float lg   = fmaxf(tg * inv_n, 0.0f);
        float lcut = fmaxf(tu * inv_n, 0.0f);
        float total = 1.0f * lc + 5.0f * lb + 2.0f * lg + 3.0f * lcut;
        out[0] = total;
        out[1] = lc;
        out[2] = lb;
        out[3] = lg;
        out[4] = lcut;
    }
}

extern "C" void kernel_launch(void* const* d_in, const int* in_sizes, int n_in,
                              void* d_out, int out_size, void* d_ws, size_t ws_size,
                              hipStream_t stream) {
    const float4* pred_logits  = (const float4*)d_in[0];
    const int*    labels       = (const int*)d_in[1];
    const float4* pred_boxes   = (const float4*)d_in[2];
    const float4* target_boxes = (const float4*)d_in[3];
    const float*  cut_logits   = (const float*)d_in[4];
    const float*  cut_targets  = (const float*)d_in[5];
    float4* ws4 = (float4*)d_ws;
    float*  out = (float*)d_out;
    const int n = in_sizes[1];  // rows

    const int grid1 = 2048;   // 8 blocks/CU nominal; 8 rows/thread (2 iters x 4 rows)
    float4* part1 = ws4;      // grid1 entries

    loss_reduce<<<grid1, BLOCK, 0, stream>>>(pred_logits, labels, pred_boxes,
                                             target_boxes, cut_logits, cut_targets,
                                             part1, n);
    finalize_all<<<1, BLOCK, 0, stream>>>(part1, grid1, out, 1.0f / (float)n);
}